// Round 4
// baseline (160.671 us; speedup 1.0000x reference)
//
#include <hip/hip_runtime.h>
#include <hip/hip_bf16.h>
#include <math.h>

typedef __bf16 bf16_t;
typedef __bf16 bf16x8 __attribute__((ext_vector_type(8)));
typedef float f32x4 __attribute__((ext_vector_type(4)));

constexpr int SS = 4096;
constexpr int DD = 1024;
constexpr int HH = 64;

#if __has_builtin(__builtin_amdgcn_exp2f)
#define EXP2F __builtin_amdgcn_exp2f
#else
#define EXP2F exp2f
#endif

static __device__ __forceinline__ f32x4 mfma16(bf16x8 a, bf16x8 b, f32x4 c) {
  return __builtin_amdgcn_mfma_f32_16x16x32_bf16(a, b, c, 0, 0, 0);
}

// ---------------- kernel 0: W -> Wt bf16 (coalesced via LDS transpose) -------------
__global__ __launch_bounds__(256) void prep_w(const float* __restrict__ wq,
                                              const float* __restrict__ wk,
                                              const float* __restrict__ wv,
                                              bf16_t* __restrict__ wt) {
  __shared__ float ls[64 * 68];
  int tid = threadIdx.x;
  int sel = blockIdx.x >> 4, kb = blockIdx.x & 15, k0 = kb * 64;
  const float* src = (sel == 0) ? wq : ((sel == 1) ? wk : wv);
  int bn = sel * 64;
#pragma unroll
  for (int i = 0; i < 4; ++i) {
    int e = tid + i * 256;
    int r = e >> 4, c4 = (e & 15) * 4;
    *(float4*)&ls[r * 68 + c4] = *(const float4*)(src + (size_t)(k0 + r) * 64 + c4);
  }
  __syncthreads();
#pragma unroll
  for (int j = 0; j < 2; ++j) {
    int e = tid + j * 256;
    int n = e >> 3, kg = e & 7;
    bf16x8 v;
#pragma unroll
    for (int t = 0; t < 8; ++t) v[t] = (bf16_t)ls[(kg * 8 + t) * 68 + n];
    *(bf16x8*)(wt + (size_t)(bn + n) * 1024 + k0 + kg * 8) = v;
  }
}

// ---------------- kernel 1: QKV GEMM — M=32 x N=96, 1024 WGs, swizzled LDS ---------
__global__ __launch_bounds__(256) void gemm_qkv(const float* __restrict__ x,
                                                const bf16_t* __restrict__ wt,
                                                bf16_t* __restrict__ qo,
                                                bf16_t* __restrict__ ko,
                                                bf16_t* __restrict__ vto) {
  __shared__ bf16_t xs[2][32 * 64];   // 8 KB, XOR-swizzled
  __shared__ bf16_t wsh[2][96 * 64];  // 24 KB, XOR-swizzled
  int tid = threadIdx.x;
  int wave = tid >> 6, lane = tid & 63, quad = lane >> 4, ml = lane & 15;
  int mh = wave >> 1, nh = wave & 1;
  int mblk = blockIdx.x >> 1, nhalf = blockIdx.x & 1;
  int m0 = mblk * 32;
  int nbase = nhalf * 96;

  f32x4 acc[3];
#pragma unroll
  for (int i = 0; i < 3; ++i) acc[i] = (f32x4){0.f, 0.f, 0.f, 0.f};

  int srow = tid >> 3, scc = tid & 7;
  float4 xr[2];
  bf16x8 wr[3];

  auto load_g = [&](int k0) {
    const float* p = x + (size_t)(m0 + srow) * DD + k0 + scc * 8;
    xr[0] = *(const float4*)p;
    xr[1] = *(const float4*)(p + 4);
#pragma unroll
    for (int i = 0; i < 3; ++i) {
      int c = tid + i * 256;
      int r = c >> 3, cc = c & 7;
      wr[i] = *(const bf16x8*)(wt + (size_t)(nbase + r) * DD + k0 + cc * 8);
    }
  };
  auto store_lds = [&](int bf) {
    bf16x8 v;
    v[0] = (bf16_t)xr[0].x; v[1] = (bf16_t)xr[0].y;
    v[2] = (bf16_t)xr[0].z; v[3] = (bf16_t)xr[0].w;
    v[4] = (bf16_t)xr[1].x; v[5] = (bf16_t)xr[1].y;
    v[6] = (bf16_t)xr[1].z; v[7] = (bf16_t)xr[1].w;
    *(bf16x8*)&xs[bf][srow * 64 + ((scc ^ (srow & 7)) * 8)] = v;
#pragma unroll
    for (int i = 0; i < 3; ++i) {
      int c = tid + i * 256;
      int r = c >> 3, cc = c & 7;
      *(bf16x8*)&wsh[bf][r * 64 + ((cc ^ (r & 7)) * 8)] = wr[i];
    }
  };

  load_g(0);
  store_lds(0);
  load_g(64);
  __syncthreads();
  for (int it = 0; it < 16; ++it) {
    int bf = it & 1;
#pragma unroll
    for (int s = 0; s < 2; ++s) {
      int rchunk = ((s * 4 + quad) ^ (ml & 7)) * 8;
      bf16x8 a = *(const bf16x8*)&xs[bf][(mh * 16 + ml) * 64 + rchunk];
#pragma unroll
      for (int i = 0; i < 3; ++i) {
        bf16x8 bfr = *(const bf16x8*)&wsh[bf][(nh * 48 + i * 16 + ml) * 64 + rchunk];
        acc[i] = mfma16(a, bfr, acc[i]);
      }
    }
    if (it < 15) {
      store_lds(1 - bf);
      if (it < 14) load_g((it + 2) * 64);
      __syncthreads();
    }
  }

  int b = m0 >> 12;
  int sr = m0 & 4095;
  const float QSCALE = 0.18033688011112042f;  // log2(e)/sqrt(64)
  bf16_t* vls = (bf16_t*)xs;
  __syncthreads();
#pragma unroll
  for (int i = 0; i < 3; ++i) {
    int col = nbase + nh * 48 + i * 16 + ml;
#pragma unroll
    for (int r = 0; r < 4; ++r) {
      int lrow = mh * 16 + quad * 4 + r;
      size_t grow = (size_t)b * SS + sr + lrow;
      if (col < 64) qo[grow * HH + col] = (bf16_t)(acc[i][r] * QSCALE);
      else if (col < 128) ko[grow * HH + (col - 64)] = (bf16_t)(acc[i][r]);
      else vls[(col - 128) * 40 + lrow] = (bf16_t)(acc[i][r]);
    }
  }
  if (nhalf == 1) {
    __syncthreads();
    int h = tid >> 2, sg = tid & 3;
    *(bf16x8*)(vto + ((size_t)b * HH + h) * SS + sr + sg * 8) =
        *(const bf16x8*)&vls[h * 40 + sg * 8];
  }
}

// ---------------- kernel 2: flash attention, chunk=8, dbuf LDS, 1 barrier/iter -----
// grid 2048: jt = 63-(bid>>5) (longest first), b=(bid>>3)&3, ch=bid&7.
// nch=(jt>>3)+1; WGs with ch>=nch exit. nch==1 (jt<8) writes direct to out.
__global__ __launch_bounds__(256) void attn_partial(const bf16_t* __restrict__ qg,
                                                    const bf16_t* __restrict__ kg,
                                                    const bf16_t* __restrict__ vg,
                                                    float* __restrict__ partO,
                                                    float* __restrict__ lb,
                                                    float* __restrict__ out) {
  __shared__ bf16_t Kl[2][64 * 64];   // 16 KB dbuf [key][h] swizzled
  __shared__ bf16_t Vl[2][64 * 64];   // 16 KB dbuf [h][key] swizzled
  __shared__ bf16_t Pl[4][16 * 64];   // 8 KB per-wave scratch
  int tid = threadIdx.x;
  int wave = tid >> 6, lane = tid & 63, quad = lane >> 4, ml = lane & 15;

  int bid = blockIdx.x;
  int jt = 63 - (bid >> 5);
  int b = (bid >> 3) & 3;
  int ch = bid & 7;
  int nch = (jt >> 3) + 1;
  if (ch >= nch) return;
  int c0 = ch * 8;
  int len = min(8, jt + 1 - c0);
  bool direct = (nch == 1);
  int q0 = jt * 64;

  const bf16_t* qb = qg + (size_t)b * SS * HH;
  const bf16_t* kb = kg + (size_t)b * SS * HH;
  const bf16_t* vb = vg + (size_t)b * HH * SS;

  int qrow = q0 + wave * 16 + ml;
  bf16x8 aq0 = *(const bf16x8*)(qb + (size_t)qrow * HH + quad * 8);
  bf16x8 aq1 = *(const bf16x8*)(qb + (size_t)qrow * HH + 32 + quad * 8);

  bf16x8 kreg[2], vreg[2];
  int srl = tid >> 3, scc = tid & 7;
  auto load_kv = [&](int kt) {
#pragma unroll
    for (int i = 0; i < 2; ++i) {
      int r = srl + i * 32;
      kreg[i] = *(const bf16x8*)(kb + (size_t)(kt * 64 + r) * HH + scc * 8);
      vreg[i] = *(const bf16x8*)(vb + (size_t)r * SS + kt * 64 + scc * 8);
    }
  };
  auto store_kv = [&](int bf) {
#pragma unroll
    for (int i = 0; i < 2; ++i) {
      int r = srl + i * 32;
      int off = r * 64 + ((scc ^ (r & 7)) * 8);
      *(bf16x8*)&Kl[bf][off] = kreg[i];
      *(bf16x8*)&Vl[bf][off] = vreg[i];
    }
  };

  f32x4 oa[4];
#pragma unroll
  for (int i = 0; i < 4; ++i) oa[i] = (f32x4){0.f, 0.f, 0.f, 0.f};
  float lr[4] = {0.f, 0.f, 0.f, 0.f};

  load_kv(c0);
  store_kv(0);

  for (int i = 0; i < len; ++i) {
    int kt = c0 + i;
    int bf = i & 1;
    __syncthreads();                    // buf bf ready; buf bf^1 reads (iter i-1) done
    if (i + 1 < len) load_kv(kt + 1);   // global loads overlap compute

    f32x4 sa[4];
#pragma unroll
    for (int nt = 0; nt < 4; ++nt) sa[nt] = (f32x4){0.f, 0.f, 0.f, 0.f};
#pragma unroll
    for (int s = 0; s < 2; ++s) {
      bf16x8 a = s ? aq1 : aq0;
      int rchunk = ((s * 4 + quad) ^ (ml & 7)) * 8;
#pragma unroll
      for (int nt = 0; nt < 4; ++nt) {
        bf16x8 bfr = *(const bf16x8*)&Kl[bf][(nt * 16 + ml) * 64 + rchunk];
        sa[nt] = mfma16(a, bfr, sa[nt]);
      }
    }

    if (kt == jt) {
#pragma unroll
      for (int nt = 0; nt < 4; ++nt) {
        int key = kt * 64 + nt * 16 + ml;
#pragma unroll
        for (int r = 0; r < 4; ++r) {
          int qr = q0 + wave * 16 + quad * 4 + r;
          if (key > qr) sa[nt][r] = -3.38953139e38f;
        }
      }
    }

    // no-max softmax (scores pre-scaled to log2 domain; bounded, fp32-safe)
#pragma unroll
    for (int r = 0; r < 4; ++r) {
      float p0 = EXP2F(sa[0][r]);
      float p1 = EXP2F(sa[1][r]);
      float p2 = EXP2F(sa[2][r]);
      float p3 = EXP2F(sa[3][r]);
      sa[0][r] = p0; sa[1][r] = p1; sa[2][r] = p2; sa[3][r] = p3;
      lr[r] += (p0 + p1) + (p2 + p3);
    }

    // P: C-layout -> A-layout via per-wave swizzled LDS (no barrier: same wave)
#pragma unroll
    for (int nt = 0; nt < 4; ++nt) {
#pragma unroll
      for (int r = 0; r < 4; ++r) {
        int row = quad * 4 + r;
        int cc = nt * 2 + (ml >> 3);
        Pl[wave][row * 64 + ((cc ^ (row & 7)) * 8) + (ml & 7)] = (bf16_t)sa[nt][r];
      }
    }
#pragma unroll
    for (int s = 0; s < 2; ++s) {
      int rchunk = ((s * 4 + quad) ^ (ml & 7)) * 8;
      bf16x8 pa = *(const bf16x8*)&Pl[wave][ml * 64 + rchunk];
#pragma unroll
      for (int ht = 0; ht < 4; ++ht) {
        bf16x8 bv = *(const bf16x8*)&Vl[bf][(ht * 16 + ml) * 64 + rchunk];
        oa[ht] = mfma16(pa, bv, oa[ht]);
      }
    }

    if (i + 1 < len) store_kv(1 - bf);  // write opposite buffer; next barrier protects
  }

#pragma unroll
  for (int r = 0; r < 4; ++r) {
    float t = lr[r];
    t += __shfl_xor(t, 1);
    t += __shfl_xor(t, 2);
    t += __shfl_xor(t, 4);
    t += __shfl_xor(t, 8);
    lr[r] = t;
  }

  if (direct) {
#pragma unroll
    for (int r = 0; r < 4; ++r) {
      float inv = 1.0f / lr[r];
      int row = q0 + wave * 16 + quad * 4 + r;
#pragma unroll
      for (int ht = 0; ht < 4; ++ht)
        out[((size_t)b * SS + row) * HH + ht * 16 + ml] = oa[ht][r] * inv;
    }
  } else {
    int slot = (b << 9) + (jt << 3) + ch;
    float* po = partO + (size_t)slot * 4096;
#pragma unroll
    for (int r = 0; r < 4; ++r) {
      int row = wave * 16 + quad * 4 + r;
#pragma unroll
      for (int ht = 0; ht < 4; ++ht)
        po[row * 64 + ht * 16 + ml] = oa[ht][r];
      if (ml == 0) lb[slot * 64 + row] = lr[r];
    }
  }
}

// ---------------- kernel 3: combine (plain sum / sum-l), up to 8 chunks ------------
__global__ __launch_bounds__(256) void combine(const float* __restrict__ partO,
                                               const float* __restrict__ lb,
                                               float* __restrict__ out) {
  int bid = blockIdx.x;  // 224 = b(4) x jt(8..63)
  int b = bid / 56;
  int jt = 8 + (bid - b * 56);
  int nch = (jt >> 3) + 1;
  int base = (b << 9) + (jt << 3);
  int tid = threadIdx.x;
  int row = tid >> 2, cb = tid & 3;

  float l = 0.f;
  f32x4 o[4];
#pragma unroll
  for (int j = 0; j < 4; ++j) o[j] = (f32x4){0.f, 0.f, 0.f, 0.f};
  for (int c = 0; c < nch; ++c) {
    l += lb[(base + c) * 64 + row];
    const f32x4* p = (const f32x4*)(partO + (size_t)(base + c) * 4096 + row * 64 + cb * 16);
#pragma unroll
    for (int j = 0; j < 4; ++j) o[j] += p[j];
  }
  float inv = 1.0f / l;
  f32x4* op = (f32x4*)(out + (((size_t)b * SS) + jt * 64 + row) * HH + cb * 16);
#pragma unroll
  for (int j = 0; j < 4; ++j) op[j] = o[j] * inv;
}

// ---------------- host ----------------
extern "C" void kernel_launch(void* const* d_in, const int* in_sizes, int n_in,
                              void* d_out, int out_size, void* d_ws, size_t ws_size,
                              hipStream_t stream) {
  const float* x  = (const float*)d_in[0];
  const float* wq = (const float*)d_in[1];
  const float* wk = (const float*)d_in[2];
  const float* wv = (const float*)d_in[3];
  float* out = (float*)d_out;

  char* wsb = (char*)d_ws;
  bf16_t* wt  = (bf16_t*)wsb;                    // 384 KB
  bf16_t* q   = (bf16_t*)(wsb + 524288);         // 2 MB
  bf16_t* k   = (bf16_t*)(wsb + 2621440);        // 2 MB
  bf16_t* vt  = (bf16_t*)(wsb + 4718592);        // 2 MB
  float*  po  = (float*)(wsb + 6815744);         // 32 MB (2048 slots x 16 KB)
  float*  lb  = (float*)(wsb + 40370176);        // 512 KB

  prep_w<<<48, 256, 0, stream>>>(wq, wk, wv, wt);
  gemm_qkv<<<1024, 256, 0, stream>>>(x, wt, q, k, vt);
  attn_partial<<<2048, 256, 0, stream>>>(q, k, vt, po, lb, out);
  combine<<<224, 256, 0, stream>>>(po, lb, out);
}

// Round 5
// 151.422 us; speedup vs baseline: 1.0611x; 1.0611x over previous
//
#include <hip/hip_runtime.h>
#include <hip/hip_bf16.h>
#include <math.h>

typedef __bf16 bf16_t;
typedef __bf16 bf16x8 __attribute__((ext_vector_type(8)));
typedef float f32x4 __attribute__((ext_vector_type(4)));

constexpr int SS = 4096;
constexpr int DD = 1024;
constexpr int HH = 64;

#if __has_builtin(__builtin_amdgcn_exp2f)
#define EXP2F __builtin_amdgcn_exp2f
#else
#define EXP2F exp2f
#endif

static __device__ __forceinline__ f32x4 mfma16(bf16x8 a, bf16x8 b, f32x4 c) {
  return __builtin_amdgcn_mfma_f32_16x16x32_bf16(a, b, c, 0, 0, 0);
}

// ---------------- kernel 0: W -> Wt bf16 (coalesced via LDS transpose) -------------
__global__ __launch_bounds__(256) void prep_w(const float* __restrict__ wq,
                                              const float* __restrict__ wk,
                                              const float* __restrict__ wv,
                                              bf16_t* __restrict__ wt) {
  __shared__ float ls[64 * 68];
  int tid = threadIdx.x;
  int sel = blockIdx.x >> 4, kb = blockIdx.x & 15, k0 = kb * 64;
  const float* src = (sel == 0) ? wq : ((sel == 1) ? wk : wv);
  int bn = sel * 64;
#pragma unroll
  for (int i = 0; i < 4; ++i) {
    int e = tid + i * 256;
    int r = e >> 4, c4 = (e & 15) * 4;
    *(float4*)&ls[r * 68 + c4] = *(const float4*)(src + (size_t)(k0 + r) * 64 + c4);
  }
  __syncthreads();
#pragma unroll
  for (int j = 0; j < 2; ++j) {
    int e = tid + j * 256;
    int n = e >> 3, kg = e & 7;
    bf16x8 v;
#pragma unroll
    for (int t = 0; t < 8; ++t) v[t] = (bf16_t)ls[(kg * 8 + t) * 68 + n];
    *(bf16x8*)(wt + (size_t)(bn + n) * 1024 + k0 + kg * 8) = v;
  }
}

// ---------------- kernel 1: QKV GEMM — M=64 x N=96, 512 WGs, dbuf, 12 mfma/wave ----
__global__ __launch_bounds__(256) void gemm_qkv(const float* __restrict__ x,
                                                const bf16_t* __restrict__ wt,
                                                bf16_t* __restrict__ qo,
                                                bf16_t* __restrict__ ko,
                                                bf16_t* __restrict__ vto) {
  __shared__ bf16_t xs[2][64 * 64];   // 16 KB dbuf, XOR-swizzled
  __shared__ bf16_t wsh[2][96 * 64];  // 24 KB dbuf, XOR-swizzled
  int tid = threadIdx.x;
  int wave = tid >> 6, lane = tid & 63, quad = lane >> 4, ml = lane & 15;
  int mblk = blockIdx.x >> 1, nhalf = blockIdx.x & 1;
  int m0 = mblk * 64;
  int nbase = nhalf * 96;

  f32x4 acc[6];
#pragma unroll
  for (int i = 0; i < 6; ++i) acc[i] = (f32x4){0.f, 0.f, 0.f, 0.f};

  int xrow = tid >> 2, xseg = tid & 3;  // each thread: 16 consecutive floats of one row
  float4 xr[4];
  bf16x8 wr[3];

  auto load_g = [&](int k0) {
    const float* p = x + (size_t)(m0 + xrow) * DD + k0 + xseg * 16;
    xr[0] = *(const float4*)p;
    xr[1] = *(const float4*)(p + 4);
    xr[2] = *(const float4*)(p + 8);
    xr[3] = *(const float4*)(p + 12);
#pragma unroll
    for (int i = 0; i < 3; ++i) {
      int c = tid + i * 256;
      int r = c >> 3, cc = c & 7;
      wr[i] = *(const bf16x8*)(wt + (size_t)(nbase + r) * DD + k0 + cc * 8);
    }
  };
  auto store_lds = [&](int bf) {
    bf16x8 v0, v1;
    v0[0] = (bf16_t)xr[0].x; v0[1] = (bf16_t)xr[0].y;
    v0[2] = (bf16_t)xr[0].z; v0[3] = (bf16_t)xr[0].w;
    v0[4] = (bf16_t)xr[1].x; v0[5] = (bf16_t)xr[1].y;
    v0[6] = (bf16_t)xr[1].z; v0[7] = (bf16_t)xr[1].w;
    v1[0] = (bf16_t)xr[2].x; v1[1] = (bf16_t)xr[2].y;
    v1[2] = (bf16_t)xr[2].z; v1[3] = (bf16_t)xr[2].w;
    v1[4] = (bf16_t)xr[3].x; v1[5] = (bf16_t)xr[3].y;
    v1[6] = (bf16_t)xr[3].z; v1[7] = (bf16_t)xr[3].w;
    int cc0 = (2 * xseg) ^ (xrow & 7);
    int cc1 = (2 * xseg + 1) ^ (xrow & 7);
    *(bf16x8*)&xs[bf][xrow * 64 + cc0 * 8] = v0;
    *(bf16x8*)&xs[bf][xrow * 64 + cc1 * 8] = v1;
#pragma unroll
    for (int i = 0; i < 3; ++i) {
      int c = tid + i * 256;
      int r = c >> 3, cc = c & 7;
      *(bf16x8*)&wsh[bf][r * 64 + ((cc ^ (r & 7)) * 8)] = wr[i];
    }
  };

  load_g(0);
  store_lds(0);
  load_g(64);
  __syncthreads();
  for (int it = 0; it < 16; ++it) {
    int bf = it & 1;
#pragma unroll
    for (int s = 0; s < 2; ++s) {
      int rchunk = ((s * 4 + quad) ^ (ml & 7)) * 8;
      bf16x8 a = *(const bf16x8*)&xs[bf][(wave * 16 + ml) * 64 + rchunk];
#pragma unroll
      for (int i = 0; i < 6; ++i) {
        bf16x8 bfr = *(const bf16x8*)&wsh[bf][(i * 16 + ml) * 64 + rchunk];
        acc[i] = mfma16(a, bfr, acc[i]);
      }
    }
    if (it < 15) {
      store_lds(1 - bf);
      if (it < 14) load_g((it + 2) * 64);
      __syncthreads();
    }
  }

  int b = m0 >> 12;
  int sr = m0 & 4095;
  const float QSCALE = 0.18033688011112042f;  // log2(e)/sqrt(64)
  bf16_t* vls = (bf16_t*)wsh;                 // overlay: 64 h x 72 stride = 9 KB
#pragma unroll
  for (int i = 0; i < 6; ++i) {
    int col = nbase + i * 16 + ml;
#pragma unroll
    for (int r = 0; r < 4; ++r) {
      int lrow = wave * 16 + quad * 4 + r;
      size_t grow = (size_t)b * SS + sr + lrow;
      if (col < 64) qo[grow * HH + col] = (bf16_t)(acc[i][r] * QSCALE);
      else if (col < 128) ko[grow * HH + (col - 64)] = (bf16_t)(acc[i][r]);
      else vls[(col - 128) * 72 + lrow] = (bf16_t)(acc[i][r]);
    }
  }
  __syncthreads();
  if (nhalf == 1) {
    int h = tid >> 2, sg = tid & 3;  // 64 h x 64 rows, 2x16B per thread
    *(bf16x8*)(vto + ((size_t)b * HH + h) * SS + sr + sg * 16) =
        *(const bf16x8*)&vls[h * 72 + sg * 16];
    *(bf16x8*)(vto + ((size_t)b * HH + h) * SS + sr + sg * 16 + 8) =
        *(const bf16x8*)&vls[h * 72 + sg * 16 + 8];
  }
}

// ---------------- kernel 2: flash attention, chunk=16, dbuf LDS, 1 barrier/iter ----
// grid 832: bid<768 -> (jt>=16, 4 chunks); bid>=768 -> jt<16 direct to out.
__global__ __launch_bounds__(256) void attn_partial(const bf16_t* __restrict__ qg,
                                                    const bf16_t* __restrict__ kg,
                                                    const bf16_t* __restrict__ vg,
                                                    float* __restrict__ partO,
                                                    float* __restrict__ lb,
                                                    float* __restrict__ out) {
  __shared__ bf16_t Kl[2][64 * 64];   // 16 KB dbuf [key][h] swizzled
  __shared__ bf16_t Vl[2][64 * 64];   // 16 KB dbuf [h][key] swizzled
  __shared__ bf16_t Pl[4][16 * 64];   // 8 KB per-wave scratch
  int tid = threadIdx.x;
  int wave = tid >> 6, lane = tid & 63, quad = lane >> 4, ml = lane & 15;

  int bid = blockIdx.x;
  int b, jt, c0, len, slot = 0;
  bool direct;
  if (bid < 768) {
    jt = 63 - (bid >> 4);
    int rem = bid & 15;
    b = rem >> 2;
    int ch = rem & 3;
    int L = (jt + 4) >> 2;
    c0 = ch * L;
    int c1 = c0 + L; if (c1 > jt + 1) c1 = jt + 1;
    len = c1 - c0;
    slot = (b * 48 + (jt - 16)) * 4 + ch;
    direct = false;
  } else {
    int idx = bid - 768;
    jt = 15 - (idx >> 2);
    b = idx & 3;
    c0 = 0;
    len = jt + 1;
    direct = true;
  }
  int q0 = jt * 64;

  const bf16_t* qb = qg + (size_t)b * SS * HH;
  const bf16_t* kb = kg + (size_t)b * SS * HH;
  const bf16_t* vb = vg + (size_t)b * HH * SS;

  int qrow = q0 + wave * 16 + ml;
  bf16x8 aq0 = *(const bf16x8*)(qb + (size_t)qrow * HH + quad * 8);
  bf16x8 aq1 = *(const bf16x8*)(qb + (size_t)qrow * HH + 32 + quad * 8);

  bf16x8 kreg[2], vreg[2];
  int srl = tid >> 3, scc = tid & 7;
  auto load_kv = [&](int kt) {
#pragma unroll
    for (int i = 0; i < 2; ++i) {
      int r = srl + i * 32;
      kreg[i] = *(const bf16x8*)(kb + (size_t)(kt * 64 + r) * HH + scc * 8);
      vreg[i] = *(const bf16x8*)(vb + (size_t)r * SS + kt * 64 + scc * 8);
    }
  };
  auto store_kv = [&](int bf) {
#pragma unroll
    for (int i = 0; i < 2; ++i) {
      int r = srl + i * 32;
      int off = r * 64 + ((scc ^ (r & 7)) * 8);
      *(bf16x8*)&Kl[bf][off] = kreg[i];
      *(bf16x8*)&Vl[bf][off] = vreg[i];
    }
  };

  f32x4 oa[4];
#pragma unroll
  for (int i = 0; i < 4; ++i) oa[i] = (f32x4){0.f, 0.f, 0.f, 0.f};
  float lr[4] = {0.f, 0.f, 0.f, 0.f};

  load_kv(c0);
  store_kv(0);

  for (int i = 0; i < len; ++i) {
    int kt = c0 + i;
    int bf = i & 1;
    __syncthreads();                    // buf bf ready; prior reads of bf done
    if (i + 1 < len) load_kv(kt + 1);   // next tile's global loads in flight

    f32x4 sa[4];
#pragma unroll
    for (int nt = 0; nt < 4; ++nt) sa[nt] = (f32x4){0.f, 0.f, 0.f, 0.f};
#pragma unroll
    for (int s = 0; s < 2; ++s) {
      bf16x8 a = s ? aq1 : aq0;
      int rchunk = ((s * 4 + quad) ^ (ml & 7)) * 8;
#pragma unroll
      for (int nt = 0; nt < 4; ++nt) {
        bf16x8 bfr = *(const bf16x8*)&Kl[bf][(nt * 16 + ml) * 64 + rchunk];
        sa[nt] = mfma16(a, bfr, sa[nt]);
      }
    }

    if (kt == jt) {
#pragma unroll
      for (int nt = 0; nt < 4; ++nt) {
        int key = kt * 64 + nt * 16 + ml;
#pragma unroll
        for (int r = 0; r < 4; ++r) {
          int qr = q0 + wave * 16 + quad * 4 + r;
          if (key > qr) sa[nt][r] = -3.38953139e38f;
        }
      }
    }

    // no-max softmax (log2-domain scores are bounded; fp32-safe)
#pragma unroll
    for (int r = 0; r < 4; ++r) {
      float p0 = EXP2F(sa[0][r]);
      float p1 = EXP2F(sa[1][r]);
      float p2 = EXP2F(sa[2][r]);
      float p3 = EXP2F(sa[3][r]);
      sa[0][r] = p0; sa[1][r] = p1; sa[2][r] = p2; sa[3][r] = p3;
      lr[r] += (p0 + p1) + (p2 + p3);
    }

    // P: C-layout -> A-layout via per-wave swizzled LDS (same-wave, no barrier)
#pragma unroll
    for (int nt = 0; nt < 4; ++nt) {
#pragma unroll
      for (int r = 0; r < 4; ++r) {
        int row = quad * 4 + r;
        int cc = nt * 2 + (ml >> 3);
        Pl[wave][row * 64 + ((cc ^ (row & 7)) * 8) + (ml & 7)] = (bf16_t)sa[nt][r];
      }
    }
#pragma unroll
    for (int s = 0; s < 2; ++s) {
      int rchunk = ((s * 4 + quad) ^ (ml & 7)) * 8;
      bf16x8 pa = *(const bf16x8*)&Pl[wave][ml * 64 + rchunk];
#pragma unroll
      for (int ht = 0; ht < 4; ++ht) {
        bf16x8 bv = *(const bf16x8*)&Vl[bf][(ht * 16 + ml) * 64 + rchunk];
        oa[ht] = mfma16(pa, bv, oa[ht]);
      }
    }

    if (i + 1 < len) store_kv(1 - bf);  // opposite buffer; next barrier protects
  }

#pragma unroll
  for (int r = 0; r < 4; ++r) {
    float t = lr[r];
    t += __shfl_xor(t, 1);
    t += __shfl_xor(t, 2);
    t += __shfl_xor(t, 4);
    t += __shfl_xor(t, 8);
    lr[r] = t;
  }

  if (direct) {
#pragma unroll
    for (int r = 0; r < 4; ++r) {
      float inv = 1.0f / lr[r];
      int row = q0 + wave * 16 + quad * 4 + r;
#pragma unroll
      for (int ht = 0; ht < 4; ++ht)
        out[((size_t)b * SS + row) * HH + ht * 16 + ml] = oa[ht][r] * inv;
    }
  } else {
    float* po = partO + (size_t)slot * 4096;
#pragma unroll
    for (int r = 0; r < 4; ++r) {
      int row = wave * 16 + quad * 4 + r;
#pragma unroll
      for (int ht = 0; ht < 4; ++ht)
        po[row * 64 + ht * 16 + ml] = oa[ht][r];
      if (ml == 0) lb[slot * 64 + row] = lr[r];
    }
  }
}

// ---------------- kernel 3: combine (plain sum / sum-l), 4 chunks ------------------
__global__ __launch_bounds__(256) void combine(const float* __restrict__ partO,
                                               const float* __restrict__ lb,
                                               float* __restrict__ out) {
  int bid = blockIdx.x;  // 384 = b(4) x jt(48) x half(2)
  int b = bid / 96;
  int rest = bid - b * 96;
  int jt = 16 + (rest >> 1), half = rest & 1;
  int base = (b * 48 + (jt - 16)) * 4;
  int tid = threadIdx.x;
  int lr_ = tid >> 3, cb = tid & 7;
  int row = half * 32 + lr_;

  float l = 0.f;
  float4 o0 = {0.f, 0.f, 0.f, 0.f}, o1 = {0.f, 0.f, 0.f, 0.f};
#pragma unroll
  for (int c = 0; c < 4; ++c) {
    l += lb[(base + c) * 64 + row];
    const float* p = partO + (size_t)(base + c) * 4096 + row * 64 + cb * 8;
    float4 a = *(const float4*)p;
    float4 bq = *(const float4*)(p + 4);
    o0.x += a.x; o0.y += a.y; o0.z += a.z; o0.w += a.w;
    o1.x += bq.x; o1.y += bq.y; o1.z += bq.z; o1.w += bq.w;
  }
  float inv = 1.0f / l;
  float* op = out + (((size_t)b * SS) + jt * 64 + row) * HH + cb * 8;
  o0.x *= inv; o0.y *= inv; o0.z *= inv; o0.w *= inv;
  o1.x *= inv; o1.y *= inv; o1.z *= inv; o1.w *= inv;
  *(float4*)op = o0;
  *(float4*)(op + 4) = o1;
}

// ---------------- host ----------------
extern "C" void kernel_launch(void* const* d_in, const int* in_sizes, int n_in,
                              void* d_out, int out_size, void* d_ws, size_t ws_size,
                              hipStream_t stream) {
  const float* x  = (const float*)d_in[0];
  const float* wq = (const float*)d_in[1];
  const float* wk = (const float*)d_in[2];
  const float* wv = (const float*)d_in[3];
  float* out = (float*)d_out;

  char* wsb = (char*)d_ws;
  bf16_t* wt  = (bf16_t*)wsb;                    // 384 KB
  bf16_t* q   = (bf16_t*)(wsb + 524288);         // 2 MB
  bf16_t* k   = (bf16_t*)(wsb + 2621440);        // 2 MB
  bf16_t* vt  = (bf16_t*)(wsb + 4718592);        // 2 MB
  float*  po  = (float*)(wsb + 6815744);         // 12.6 MB (768 slots x 16 KB)
  float*  lb  = (float*)(wsb + 19398656);        // 196 KB

  prep_w<<<48, 256, 0, stream>>>(wq, wk, wv, wt);
  gemm_qkv<<<512, 256, 0, stream>>>(x, wt, q, k, vt);
  attn_partial<<<832, 256, 0, stream>>>(q, k, vt, po, lb, out);
  combine<<<384, 256, 0, stream>>>(po, lb, out);
}